// Round 6
// baseline (196.351 us; speedup 1.0000x reference)
//
#include <hip/hip_runtime.h>
#include <hip/hip_fp16.h>
#include <math.h>

#define BB 8  // batch count (fixed by problem instance)

typedef float f32x2 __attribute__((ext_vector_type(2)));

__device__ __forceinline__ float sigmoidf_(float v) {
    // raw v_rcp_f32 (~1 ULP) instead of IEEE division chain
    return __builtin_amdgcn_rcpf(1.0f + __expf(-v));
}

// ---- K1 (fused): edge_attr stats partials + histogram + within-node rank ----
__global__ void stats_rel_kernel(const float* __restrict__ ea, const int* __restrict__ ei,
                                 int E, double* __restrict__ acc, int* __restrict__ cnt,
                                 int* __restrict__ rel_t, int* __restrict__ rel_s) {
    __shared__ double sh[4][256];
    int tid = threadIdx.x;
    double s0 = 0, q0 = 0, s1 = 0, q1 = 0;
    for (int i = blockIdx.x * blockDim.x + tid; i < E; i += gridDim.x * blockDim.x) {
        float a = ea[2 * i];
        float b = ea[2 * i + 1];
        s0 += (double)a; q0 += (double)a * (double)a;
        s1 += (double)b; q1 += (double)b * (double)b;
        rel_t[i] = atomicAdd(&cnt[ei[E + i]], 1);  // tgt (+g)
        rel_s[i] = atomicAdd(&cnt[ei[i]], 1);      // src (-g)
    }
    sh[0][tid] = s0; sh[1][tid] = q0; sh[2][tid] = s1; sh[3][tid] = q1;
    __syncthreads();
    for (int off = 128; off > 0; off >>= 1) {
        if (tid < off) {
            sh[0][tid] += sh[0][tid + off];
            sh[1][tid] += sh[1][tid + off];
            sh[2][tid] += sh[2][tid + off];
            sh[3][tid] += sh[3][tid + off];
        }
        __syncthreads();
    }
    if (tid == 0) {
        atomicAdd(&acc[0], sh[0][0]);
        atomicAdd(&acc[1], sh[1][0]);
        atomicAdd(&acc[2], sh[2][0]);
        atomicAdd(&acc[3], sh[3][0]);
    }
}

// ---- K2 (fused): exclusive scan over node counts + stats finalize ----
__global__ __launch_bounds__(1024) void scan_kernel(const int* __restrict__ cnt,
                                                    int* __restrict__ off, int N,
                                                    const double* __restrict__ acc, int E,
                                                    float* __restrict__ stats) {
    if (threadIdx.x == 0) {
        double s0 = acc[0], q0 = acc[1], s1 = acc[2], q1 = acc[3];
        double v0 = (q0 - s0 * s0 / E) / (double)(E - 1);
        double v1 = (q1 - s1 * s1 / E) / (double)(E - 1);
        stats[0] = (float)(s0 / E);
        stats[1] = (float)(1.0 / sqrt(v0));
        stats[2] = (float)(s1 / E);
        stats[3] = (float)(1.0 / sqrt(v1));
    }
    __shared__ int sh[1024];
    int t = threadIdx.x;
    int chunk = (N + 1023) >> 10;
    int lo = t * chunk;
    int hi = lo + chunk; if (hi > N) hi = N;
    int s = 0;
    for (int i = lo; i < hi; i++) s += cnt[i];
    sh[t] = s;
    __syncthreads();
    for (int d = 1; d < 1024; d <<= 1) {
        int v = (t >= d) ? sh[t - d] : 0;
        __syncthreads();
        sh[t] += v;
        __syncthreads();
    }
    int run = (t == 0) ? 0 : sh[t - 1];
    for (int i = lo; i < hi; i++) {
        off[i] = run;
        run += cnt[i];
    }
    if (t == 1023) off[N] = sh[1023];
}

// ---- the 9->16->30->(@W3) MLP: packed fp32 FMA, scalar weight loads ----
__device__ __forceinline__ void mlp_eval(
    const float feat[9],
    const float* __restrict__ W1, const float* __restrict__ b1,
    const float* __restrict__ W2, const float* __restrict__ b2,
    const float* __restrict__ W3,
    float& g0, float& g1, float& g2)
{
    const f32x2* W1p = (const f32x2*)W1;   // [9][8] pairs along j
    const f32x2* b1p = (const f32x2*)b1;
    f32x2 acc1[8];
    #pragma unroll
    for (int j = 0; j < 8; j++) acc1[j] = b1p[j];
    #pragma unroll
    for (int k = 0; k < 9; k++) {
        f32x2 fk2 = {feat[k], feat[k]};
        #pragma unroll
        for (int j = 0; j < 8; j++)
            acc1[j] = __builtin_elementwise_fma(fk2, W1p[k * 8 + j], acc1[j]);
    }
    float h1[16];
    #pragma unroll
    for (int j = 0; j < 8; j++) {
        h1[2 * j]     = sigmoidf_(acc1[j].x);
        h1[2 * j + 1] = sigmoidf_(acc1[j].y);
    }

    const f32x2* W2p = (const f32x2*)W2;   // [16][15] pairs along k
    const f32x2* b2p = (const f32x2*)b2;
    f32x2 acc2[15];
    #pragma unroll
    for (int k = 0; k < 15; k++) acc2[k] = b2p[k];
    #pragma unroll
    for (int j = 0; j < 16; j++) {
        f32x2 hj2 = {h1[j], h1[j]};
        #pragma unroll
        for (int k = 0; k < 15; k++)
            acc2[k] = __builtin_elementwise_fma(hj2, W2p[j * 15 + k], acc2[k]);
    }

    g0 = 0.f; g1 = 0.f; g2 = 0.f;
    #pragma unroll
    for (int k = 0; k < 15; k++) {
        float ha = sigmoidf_(acc2[k].x);
        float hb = sigmoidf_(acc2[k].y);
        int ka = 2 * k, kb = 2 * k + 1;
        g0 = fmaf(ha, W3[ka * 3 + 0], g0); g0 = fmaf(hb, W3[kb * 3 + 0], g0);
        g1 = fmaf(ha, W3[ka * 3 + 1], g1); g1 = fmaf(hb, W3[kb * 3 + 1], g1);
        g2 = fmaf(ha, W3[ka * 3 + 2], g2); g2 = fmaf(hb, W3[kb * 3 + 2], g2);
    }
}

// ---- K3: one thread per edge, all 8 batches; line-local gbuf writes ----
// gbuf layout: [E][BB] uint2 -> each edge owns exactly one 64B line.
__global__ __launch_bounds__(256) void edge_mlp8_kernel(
    const float* __restrict__ x, const int* __restrict__ ei,
    const float* __restrict__ ea,
    const float* __restrict__ wmean, const float* __restrict__ wstd,
    const float* __restrict__ W1, const float* __restrict__ b1,
    const float* __restrict__ W2, const float* __restrict__ b2,
    const float* __restrict__ W3,
    const float* __restrict__ stats,
    const int* __restrict__ rel_t, const int* __restrict__ rel_s,
    const int* __restrict__ off,
    uint2* __restrict__ gbuf, int* __restrict__ list,
    int N, int E)
{
    int e = blockIdx.x * 256 + threadIdx.x;
    if (e >= E) return;

    int src = ei[e];
    int tgt = ei[E + e];
    float dist = ea[2 * e];
    float cdir = ea[2 * e + 1];
    float ea0 = (dist - stats[0]) * stats[1];
    float ea1 = (cdir - stats[2]) * stats[3];
    float inv3d = 3.0f * __builtin_amdgcn_rcpf(dist);
    float wm0 = wmean[0], wm1 = wmean[1];
    float wsd0 = wstd[0], wsd1 = wstd[1];

    // slot assignment + list entries (sign in MSB: set => src side, -g)
    list[off[tgt] + rel_t[e]] = e;
    list[off[src] + rel_s[e]] = e | 0x80000000;

    uint2* gb = gbuf + (size_t)e * BB;
    for (int b = 0; b < BB; b++) {
        const float* xb = x + (size_t)b * N * 3;
        float s0 = xb[src * 3 + 0], s1 = xb[src * 3 + 1], s2 = xb[src * 3 + 2];
        float t0 = xb[tgt * 3 + 0], t1 = xb[tgt * 3 + 1], t2 = xb[tgt * 3 + 2];
        float speed = fmaf(s1, wsd0, wm0);
        float direc = fmaf(s2, wsd1, wm1);
        float theta = fabsf(cdir - direc);
        float ew = fmaxf(0.0f, speed * __cosf(theta) * inv3d);

        float feat[9] = {s0, s1, s2, t0, t1, t2, ea0, ea1, ew};
        float g0, g1, g2;
        mlp_eval(feat, W1, b1, W2, b2, W3, g0, g1, g2);

        __half2 p01 = __floats2half2_rn(g0, g1);
        __half2 p2x = __floats2half2_rn(g2, 0.0f);
        uint2 wp; wp.x = *reinterpret_cast<unsigned int*>(&p01);
                  wp.y = *reinterpret_cast<unsigned int*>(&p2x);
        gb[b] = wp;
    }
}

// ---- K4: per-(node,batch) segment sum + bias + sigmoid ----
// pair = node*8+b: the 4 groups of a wave share one node (b 0-3 / 4-7),
// so list reads are identical across groups and gbuf reads hit shared 64B lines.
__global__ __launch_bounds__(256) void segment_sum_kernel(
    const uint2* __restrict__ gbuf, const int* __restrict__ off,
    const int* __restrict__ list,
    const float* __restrict__ b3, float* __restrict__ out, int N)
{
    int tid = threadIdx.x;
    int grp = tid >> 4, sub = tid & 15;
    int pair = blockIdx.x * 16 + grp;
    int node = pair >> 3, b = pair & 7;   // BB == 8
    if (node >= N) return;

    int o0 = off[node], o1 = off[node + 1];

    float a0 = 0.f, a1 = 0.f, a2 = 0.f;
    for (int i = o0 + sub; i < o1; i += 16) {
        int entry = list[i];
        int e = entry & 0x7FFFFFFF;
        float sgn = (entry < 0) ? -1.0f : 1.0f;
        uint2 w = gbuf[(size_t)e * BB + b];
        __half2 h01 = *reinterpret_cast<__half2*>(&w.x);
        __half2 h2x = *reinterpret_cast<__half2*>(&w.y);
        float2 f01 = __half22float2(h01);
        float2 f2x = __half22float2(h2x);
        a0 = fmaf(sgn, f01.x, a0);
        a1 = fmaf(sgn, f01.y, a1);
        a2 = fmaf(sgn, f2x.x, a2);
    }
    #pragma unroll
    for (int m = 8; m >= 1; m >>= 1) {
        a0 += __shfl_xor(a0, m);
        a1 += __shfl_xor(a1, m);
        a2 += __shfl_xor(a2, m);
    }
    if (sub == 0) {
        float* o = out + ((size_t)b * N + node) * 3;
        o[0] = sigmoidf_(a0 + b3[0]);
        o[1] = sigmoidf_(a1 + b3[1]);
        o[2] = sigmoidf_(a2 + b3[2]);
    }
}

// ---- Fallback (small ws): atomic-scatter path ----
__global__ __launch_bounds__(256) void edge_atomic_kernel(
    const float* __restrict__ x, const int* __restrict__ ei,
    const float* __restrict__ ea,
    const float* __restrict__ wmean, const float* __restrict__ wstd,
    const float* __restrict__ W1, const float* __restrict__ b1,
    const float* __restrict__ W2, const float* __restrict__ b2,
    const float* __restrict__ W3,
    const float* __restrict__ stats,
    float* __restrict__ out, int N, int E)
{
    int e = blockIdx.x * blockDim.x + threadIdx.x;
    if (e >= E) return;
    int src = ei[e];
    int tgt = ei[E + e];
    float dist = ea[2 * e];
    float cdir = ea[2 * e + 1];
    float ea0 = (dist - stats[0]) * stats[1];
    float ea1 = (cdir - stats[2]) * stats[3];

    for (int b = 0; b < BB; b++) {
        const float* xb = x + (size_t)b * N * 3;
        float s0 = xb[src * 3 + 0], s1 = xb[src * 3 + 1], s2 = xb[src * 3 + 2];
        float t0 = xb[tgt * 3 + 0], t1 = xb[tgt * 3 + 1], t2 = xb[tgt * 3 + 2];
        float speed = fmaf(s1, wstd[0], wmean[0]);
        float direc = fmaf(s2, wstd[1], wmean[1]);
        float theta = fabsf(cdir - direc);
        float ew = fmaxf(0.0f, speed * __cosf(theta) * 3.0f * __builtin_amdgcn_rcpf(dist));
        float feat[9] = {s0, s1, s2, t0, t1, t2, ea0, ea1, ew};
        float g0, g1, g2;
        mlp_eval(feat, W1, b1, W2, b2, W3, g0, g1, g2);
        float* ot = out + ((size_t)b * N + tgt) * 3;
        float* os = out + ((size_t)b * N + src) * 3;
        atomicAdd(&ot[0], g0);  atomicAdd(&ot[1], g1);  atomicAdd(&ot[2], g2);
        atomicAdd(&os[0], -g0); atomicAdd(&os[1], -g1); atomicAdd(&os[2], -g2);
    }
}

__global__ void output_kernel(float* __restrict__ out, const float* __restrict__ b3, int total) {
    int i = blockIdx.x * blockDim.x + threadIdx.x;
    if (i < total) out[i] = sigmoidf_(out[i] + b3[i % 3]);
}

extern "C" void kernel_launch(void* const* d_in, const int* in_sizes, int n_in,
                              void* d_out, int out_size, void* d_ws, size_t ws_size,
                              hipStream_t stream) {
    const float* x     = (const float*)d_in[0];
    const int*   ei    = (const int*)d_in[1];
    const float* ea    = (const float*)d_in[2];
    const float* wmean = (const float*)d_in[3];
    const float* wstd  = (const float*)d_in[4];
    const float* W1    = (const float*)d_in[5];
    const float* b1    = (const float*)d_in[6];
    const float* W2    = (const float*)d_in[7];
    const float* b2    = (const float*)d_in[8];
    const float* W3    = (const float*)d_in[9];
    const float* b3    = (const float*)d_in[10];

    int E = in_sizes[2] / 2;        // edge_attr is (E, 2)
    int N = in_sizes[0] / (BB * 3); // x is (B, N, 3)

    float* out = (float*)d_out;
    char* ws = (char*)d_ws;

    // layout: [cnt N][acc 4 dbl][stats 4 f][off N+1][rel_t E][rel_s E][list 2E][gbuf E*BB uint2]
    size_t cntBytes = (((size_t)N * 4) + 63) & ~(size_t)63;
    int*    cnt   = (int*)ws;
    double* acc   = (double*)(ws + cntBytes);        // 32 B
    float*  stats = (float*)(ws + cntBytes + 32);    // 16 B
    int*    off   = (int*)(ws + cntBytes + 64);      // N+1
    int*    rel_t = off + N + 1;                     // E
    int*    rel_s = rel_t + E;                       // E
    int*    list  = rel_s + E;                       // 2E

    size_t head = cntBytes + 64 + sizeof(int) * ((size_t)(N + 1) + 4 * (size_t)E);
    head = (head + 255) & ~(size_t)255;
    uint2* gbuf = (uint2*)(ws + head);
    size_t needed = head + (size_t)E * BB * sizeof(uint2);

    int eblocks = (E + 255) / 256;

    if (needed <= ws_size) {
        hipMemsetAsync(ws, 0, cntBytes + 32, stream);  // zero cnt + acc
        stats_rel_kernel<<<256, 256, 0, stream>>>(ea, ei, E, acc, cnt, rel_t, rel_s);
        scan_kernel<<<1, 1024, 0, stream>>>(cnt, off, N, acc, E, stats);
        edge_mlp8_kernel<<<eblocks, 256, 0, stream>>>(
            x, ei, ea, wmean, wstd, W1, b1, W2, b2, W3, stats,
            rel_t, rel_s, off, gbuf, list, N, E);
        int pairs = N * BB;
        segment_sum_kernel<<<(pairs + 15) / 16, 256, 0, stream>>>(
            gbuf, off, list, b3, out, N);
    } else {
        hipMemsetAsync(ws, 0, cntBytes + 32, stream);
        hipMemsetAsync(d_out, 0, (size_t)out_size * sizeof(float), stream);
        stats_rel_kernel<<<256, 256, 0, stream>>>(ea, ei, E, acc, cnt, rel_t, rel_s);
        scan_kernel<<<1, 1024, 0, stream>>>(cnt, off, N, acc, E, stats);
        edge_atomic_kernel<<<eblocks, 256, 0, stream>>>(
            x, ei, ea, wmean, wstd, W1, b1, W2, b2, W3, stats, out, N, E);
        output_kernel<<<(out_size + 255) / 256, 256, 0, stream>>>(out, b3, out_size);
    }
}

// Round 7
// 189.443 us; speedup vs baseline: 1.0365x; 1.0365x over previous
//
#include <hip/hip_runtime.h>
#include <hip/hip_fp16.h>
#include <math.h>

#define BB 8  // batch count (fixed by problem instance)

typedef float f32x2 __attribute__((ext_vector_type(2)));

__device__ __forceinline__ float sigmoidf_(float v) {
    // raw v_rcp_f32 (~1 ULP) instead of IEEE division chain
    return __builtin_amdgcn_rcpf(1.0f + __expf(-v));
}

// swizzled gbuf index: wave-coalesced writes (consecutive e, fixed b),
// 64B-line locality preserved per 32-edge chunk. Requires nothing of E
// beyond gbuf sized ceil32(E)*8 slots.
__device__ __forceinline__ int gidx(int e, int b) {
    return ((e >> 5) << 8) | (b << 5) | (e & 31);
}

// ---- K1 (fused): edge_attr stats partials + histogram + within-node rank ----
__global__ void stats_rel_kernel(const float* __restrict__ ea, const int* __restrict__ ei,
                                 int E, double* __restrict__ acc, int* __restrict__ cnt,
                                 int* __restrict__ rel_t, int* __restrict__ rel_s) {
    __shared__ double sh[4][256];
    int tid = threadIdx.x;
    double s0 = 0, q0 = 0, s1 = 0, q1 = 0;
    for (int i = blockIdx.x * blockDim.x + tid; i < E; i += gridDim.x * blockDim.x) {
        float a = ea[2 * i];
        float b = ea[2 * i + 1];
        s0 += (double)a; q0 += (double)a * (double)a;
        s1 += (double)b; q1 += (double)b * (double)b;
        rel_t[i] = atomicAdd(&cnt[ei[E + i]], 1);  // tgt (+g)
        rel_s[i] = atomicAdd(&cnt[ei[i]], 1);      // src (-g)
    }
    sh[0][tid] = s0; sh[1][tid] = q0; sh[2][tid] = s1; sh[3][tid] = q1;
    __syncthreads();
    for (int off = 128; off > 0; off >>= 1) {
        if (tid < off) {
            sh[0][tid] += sh[0][tid + off];
            sh[1][tid] += sh[1][tid + off];
            sh[2][tid] += sh[2][tid + off];
            sh[3][tid] += sh[3][tid + off];
        }
        __syncthreads();
    }
    if (tid == 0) {
        atomicAdd(&acc[0], sh[0][0]);
        atomicAdd(&acc[1], sh[1][0]);
        atomicAdd(&acc[2], sh[2][0]);
        atomicAdd(&acc[3], sh[3][0]);
    }
}

// ---- K2 (fused): exclusive scan over node counts + stats finalize ----
__global__ __launch_bounds__(1024) void scan_kernel(const int* __restrict__ cnt,
                                                    int* __restrict__ off, int N,
                                                    const double* __restrict__ acc, int E,
                                                    float* __restrict__ stats) {
    if (threadIdx.x == 0) {
        double s0 = acc[0], q0 = acc[1], s1 = acc[2], q1 = acc[3];
        double v0 = (q0 - s0 * s0 / E) / (double)(E - 1);
        double v1 = (q1 - s1 * s1 / E) / (double)(E - 1);
        stats[0] = (float)(s0 / E);
        stats[1] = (float)(1.0 / sqrt(v0));
        stats[2] = (float)(s1 / E);
        stats[3] = (float)(1.0 / sqrt(v1));
    }
    __shared__ int sh[1024];
    int t = threadIdx.x;
    int chunk = (N + 1023) >> 10;
    int lo = t * chunk;
    int hi = lo + chunk; if (hi > N) hi = N;
    int s = 0;
    for (int i = lo; i < hi; i++) s += cnt[i];
    sh[t] = s;
    __syncthreads();
    for (int d = 1; d < 1024; d <<= 1) {
        int v = (t >= d) ? sh[t - d] : 0;
        __syncthreads();
        sh[t] += v;
        __syncthreads();
    }
    int run = (t == 0) ? 0 : sh[t - 1];
    for (int i = lo; i < hi; i++) {
        off[i] = run;
        run += cnt[i];
    }
    if (t == 1023) off[N] = sh[1023];
}

// ---- the 9->16->30->(@W3) MLP: packed fp32 FMA, scalar weight loads ----
__device__ __forceinline__ void mlp_eval(
    const float feat[9],
    const float* __restrict__ W1, const float* __restrict__ b1,
    const float* __restrict__ W2, const float* __restrict__ b2,
    const float* __restrict__ W3,
    float& g0, float& g1, float& g2)
{
    const f32x2* W1p = (const f32x2*)W1;   // [9][8] pairs along j
    const f32x2* b1p = (const f32x2*)b1;
    f32x2 acc1[8];
    #pragma unroll
    for (int j = 0; j < 8; j++) acc1[j] = b1p[j];
    #pragma unroll
    for (int k = 0; k < 9; k++) {
        f32x2 fk2 = {feat[k], feat[k]};
        #pragma unroll
        for (int j = 0; j < 8; j++)
            acc1[j] = __builtin_elementwise_fma(fk2, W1p[k * 8 + j], acc1[j]);
    }
    float h1[16];
    #pragma unroll
    for (int j = 0; j < 8; j++) {
        h1[2 * j]     = sigmoidf_(acc1[j].x);
        h1[2 * j + 1] = sigmoidf_(acc1[j].y);
    }

    const f32x2* W2p = (const f32x2*)W2;   // [16][15] pairs along k
    const f32x2* b2p = (const f32x2*)b2;
    f32x2 acc2[15];
    #pragma unroll
    for (int k = 0; k < 15; k++) acc2[k] = b2p[k];
    #pragma unroll
    for (int j = 0; j < 16; j++) {
        f32x2 hj2 = {h1[j], h1[j]};
        #pragma unroll
        for (int k = 0; k < 15; k++)
            acc2[k] = __builtin_elementwise_fma(hj2, W2p[j * 15 + k], acc2[k]);
    }

    g0 = 0.f; g1 = 0.f; g2 = 0.f;
    #pragma unroll
    for (int k = 0; k < 15; k++) {
        float ha = sigmoidf_(acc2[k].x);
        float hb = sigmoidf_(acc2[k].y);
        int ka = 2 * k, kb = 2 * k + 1;
        g0 = fmaf(ha, W3[ka * 3 + 0], g0); g0 = fmaf(hb, W3[kb * 3 + 0], g0);
        g1 = fmaf(ha, W3[ka * 3 + 1], g1); g1 = fmaf(hb, W3[kb * 3 + 1], g1);
        g2 = fmaf(ha, W3[ka * 3 + 2], g2); g2 = fmaf(hb, W3[kb * 3 + 2], g2);
    }
}

// ---- K3: one thread per (edge,batch); swizzled coalesced gbuf writes ----
// grid = (ceil(E/256), BB). b==0 blocks also emit the CSR list entries.
__global__ __launch_bounds__(256) void edge_mlp_swz_kernel(
    const float* __restrict__ x, const int* __restrict__ ei,
    const float* __restrict__ ea,
    const float* __restrict__ wmean, const float* __restrict__ wstd,
    const float* __restrict__ W1, const float* __restrict__ b1,
    const float* __restrict__ W2, const float* __restrict__ b2,
    const float* __restrict__ W3,
    const float* __restrict__ stats,
    const int* __restrict__ rel_t, const int* __restrict__ rel_s,
    const int* __restrict__ off,
    uint2* __restrict__ gbuf, int* __restrict__ list,
    int N, int E)
{
    int e = blockIdx.x * 256 + threadIdx.x;
    int b = blockIdx.y;
    if (e >= E) return;

    int src = ei[e];
    int tgt = ei[E + e];

    if (b == 0) {
        // slot assignment + list entries (sign in MSB: set => src side, -g)
        list[off[tgt] + rel_t[e]] = e;
        list[off[src] + rel_s[e]] = e | 0x80000000;
    }

    float dist = ea[2 * e];
    float cdir = ea[2 * e + 1];
    float ea0 = (dist - stats[0]) * stats[1];
    float ea1 = (cdir - stats[2]) * stats[3];

    const float* xb = x + (size_t)b * N * 3;
    float s0 = xb[src * 3 + 0], s1 = xb[src * 3 + 1], s2 = xb[src * 3 + 2];
    float t0 = xb[tgt * 3 + 0], t1 = xb[tgt * 3 + 1], t2 = xb[tgt * 3 + 2];
    float speed = fmaf(s1, wstd[0], wmean[0]);
    float direc = fmaf(s2, wstd[1], wmean[1]);
    float theta = fabsf(cdir - direc);
    float ew = fmaxf(0.0f, speed * __cosf(theta) * 3.0f * __builtin_amdgcn_rcpf(dist));

    float feat[9] = {s0, s1, s2, t0, t1, t2, ea0, ea1, ew};
    float g0, g1, g2;
    mlp_eval(feat, W1, b1, W2, b2, W3, g0, g1, g2);

    __half2 p01 = __floats2half2_rn(g0, g1);
    __half2 p2x = __floats2half2_rn(g2, 0.0f);
    uint2 wp; wp.x = *reinterpret_cast<unsigned int*>(&p01);
              wp.y = *reinterpret_cast<unsigned int*>(&p2x);
    gbuf[gidx(e, b)] = wp;
}

// ---- K4: per-(node,batch) segment sum + bias + sigmoid ----
// pair = node*8+b: the 4 groups of a wave share one node, so list reads are
// identical across groups (L1 broadcast).
__global__ __launch_bounds__(256) void segment_sum_kernel(
    const uint2* __restrict__ gbuf, const int* __restrict__ off,
    const int* __restrict__ list,
    const float* __restrict__ b3, float* __restrict__ out, int N)
{
    int tid = threadIdx.x;
    int grp = tid >> 4, sub = tid & 15;
    int pair = blockIdx.x * 16 + grp;
    int node = pair >> 3, b = pair & 7;   // BB == 8
    if (node >= N) return;

    int o0 = off[node], o1 = off[node + 1];

    float a0 = 0.f, a1 = 0.f, a2 = 0.f;
    for (int i = o0 + sub; i < o1; i += 16) {
        int entry = list[i];
        int e = entry & 0x7FFFFFFF;
        float sgn = (entry < 0) ? -1.0f : 1.0f;
        uint2 w = gbuf[gidx(e, b)];
        __half2 h01 = *reinterpret_cast<__half2*>(&w.x);
        __half2 h2x = *reinterpret_cast<__half2*>(&w.y);
        float2 f01 = __half22float2(h01);
        float2 f2x = __half22float2(h2x);
        a0 = fmaf(sgn, f01.x, a0);
        a1 = fmaf(sgn, f01.y, a1);
        a2 = fmaf(sgn, f2x.x, a2);
    }
    #pragma unroll
    for (int m = 8; m >= 1; m >>= 1) {
        a0 += __shfl_xor(a0, m);
        a1 += __shfl_xor(a1, m);
        a2 += __shfl_xor(a2, m);
    }
    if (sub == 0) {
        float* o = out + ((size_t)b * N + node) * 3;
        o[0] = sigmoidf_(a0 + b3[0]);
        o[1] = sigmoidf_(a1 + b3[1]);
        o[2] = sigmoidf_(a2 + b3[2]);
    }
}

// ---- Fallback (small ws): atomic-scatter path ----
__global__ __launch_bounds__(256) void edge_atomic_kernel(
    const float* __restrict__ x, const int* __restrict__ ei,
    const float* __restrict__ ea,
    const float* __restrict__ wmean, const float* __restrict__ wstd,
    const float* __restrict__ W1, const float* __restrict__ b1,
    const float* __restrict__ W2, const float* __restrict__ b2,
    const float* __restrict__ W3,
    const float* __restrict__ stats,
    float* __restrict__ out, int N, int E)
{
    int e = blockIdx.x * blockDim.x + threadIdx.x;
    if (e >= E) return;
    int src = ei[e];
    int tgt = ei[E + e];
    float dist = ea[2 * e];
    float cdir = ea[2 * e + 1];
    float ea0 = (dist - stats[0]) * stats[1];
    float ea1 = (cdir - stats[2]) * stats[3];

    for (int b = 0; b < BB; b++) {
        const float* xb = x + (size_t)b * N * 3;
        float s0 = xb[src * 3 + 0], s1 = xb[src * 3 + 1], s2 = xb[src * 3 + 2];
        float t0 = xb[tgt * 3 + 0], t1 = xb[tgt * 3 + 1], t2 = xb[tgt * 3 + 2];
        float speed = fmaf(s1, wstd[0], wmean[0]);
        float direc = fmaf(s2, wstd[1], wmean[1]);
        float theta = fabsf(cdir - direc);
        float ew = fmaxf(0.0f, speed * __cosf(theta) * 3.0f * __builtin_amdgcn_rcpf(dist));
        float feat[9] = {s0, s1, s2, t0, t1, t2, ea0, ea1, ew};
        float g0, g1, g2;
        mlp_eval(feat, W1, b1, W2, b2, W3, g0, g1, g2);
        float* ot = out + ((size_t)b * N + tgt) * 3;
        float* os = out + ((size_t)b * N + src) * 3;
        atomicAdd(&ot[0], g0);  atomicAdd(&ot[1], g1);  atomicAdd(&ot[2], g2);
        atomicAdd(&os[0], -g0); atomicAdd(&os[1], -g1); atomicAdd(&os[2], -g2);
    }
}

__global__ void output_kernel(float* __restrict__ out, const float* __restrict__ b3, int total) {
    int i = blockIdx.x * blockDim.x + threadIdx.x;
    if (i < total) out[i] = sigmoidf_(out[i] + b3[i % 3]);
}

extern "C" void kernel_launch(void* const* d_in, const int* in_sizes, int n_in,
                              void* d_out, int out_size, void* d_ws, size_t ws_size,
                              hipStream_t stream) {
    const float* x     = (const float*)d_in[0];
    const int*   ei    = (const int*)d_in[1];
    const float* ea    = (const float*)d_in[2];
    const float* wmean = (const float*)d_in[3];
    const float* wstd  = (const float*)d_in[4];
    const float* W1    = (const float*)d_in[5];
    const float* b1    = (const float*)d_in[6];
    const float* W2    = (const float*)d_in[7];
    const float* b2    = (const float*)d_in[8];
    const float* W3    = (const float*)d_in[9];
    const float* b3    = (const float*)d_in[10];

    int E = in_sizes[2] / 2;        // edge_attr is (E, 2)
    int N = in_sizes[0] / (BB * 3); // x is (B, N, 3)

    float* out = (float*)d_out;
    char* ws = (char*)d_ws;

    // layout: [cnt N][acc 4 dbl][stats 4 f][off N+1][rel_t E][rel_s E][list 2E][gbuf]
    size_t cntBytes = (((size_t)N * 4) + 63) & ~(size_t)63;
    int*    cnt   = (int*)ws;
    double* acc   = (double*)(ws + cntBytes);        // 32 B
    float*  stats = (float*)(ws + cntBytes + 32);    // 16 B
    int*    off   = (int*)(ws + cntBytes + 64);      // N+1
    int*    rel_t = off + N + 1;                     // E
    int*    rel_s = rel_t + E;                       // E
    int*    list  = rel_s + E;                       // 2E

    size_t head = cntBytes + 64 + sizeof(int) * ((size_t)(N + 1) + 4 * (size_t)E);
    head = (head + 255) & ~(size_t)255;
    uint2* gbuf = (uint2*)(ws + head);
    size_t slots = ((size_t)((E + 31) & ~31)) * BB;  // swizzled: ceil32(E)*8
    size_t needed = head + slots * sizeof(uint2);

    int eblocks = (E + 255) / 256;

    if (needed <= ws_size) {
        hipMemsetAsync(ws, 0, cntBytes + 32, stream);  // zero cnt + acc
        stats_rel_kernel<<<256, 256, 0, stream>>>(ea, ei, E, acc, cnt, rel_t, rel_s);
        scan_kernel<<<1, 1024, 0, stream>>>(cnt, off, N, acc, E, stats);
        dim3 gridA(eblocks, BB);
        edge_mlp_swz_kernel<<<gridA, 256, 0, stream>>>(
            x, ei, ea, wmean, wstd, W1, b1, W2, b2, W3, stats,
            rel_t, rel_s, off, gbuf, list, N, E);
        int pairs = N * BB;
        segment_sum_kernel<<<(pairs + 15) / 16, 256, 0, stream>>>(
            gbuf, off, list, b3, out, N);
    } else {
        hipMemsetAsync(ws, 0, cntBytes + 32, stream);
        hipMemsetAsync(d_out, 0, (size_t)out_size * sizeof(float), stream);
        stats_rel_kernel<<<256, 256, 0, stream>>>(ea, ei, E, acc, cnt, rel_t, rel_s);
        scan_kernel<<<1, 1024, 0, stream>>>(cnt, off, N, acc, E, stats);
        edge_atomic_kernel<<<eblocks, 256, 0, stream>>>(
            x, ei, ea, wmean, wstd, W1, b1, W2, b2, W3, stats, out, N, E);
        output_kernel<<<(out_size + 255) / 256, 256, 0, stream>>>(out, b3, out_size);
    }
}

// Round 8
// 149.968 us; speedup vs baseline: 1.3093x; 1.2632x over previous
//
#include <hip/hip_runtime.h>
#include <hip/hip_fp16.h>
#include <math.h>

#define BB 8  // batch count (fixed by problem instance)

typedef float f32x2 __attribute__((ext_vector_type(2)));

__device__ __forceinline__ float sigmoidf_(float v) {
    // raw v_rcp_f32 (~1 ULP) instead of IEEE division chain
    return __builtin_amdgcn_rcpf(1.0f + __expf(-v));
}

// ---- K0: transpose x[B][N][3] -> xT[N][B][3] (per-edge batch reads contiguous) ----
__global__ void transpose_x_kernel(const float* __restrict__ x, float* __restrict__ xT,
                                   int N, int total) {
    int idx = blockIdx.x * 256 + threadIdx.x;
    if (idx < total) {
        int c = idx % 3;
        int rest = idx / 3;
        int n = rest % N;
        int b = rest / N;
        xT[n * 24 + b * 3 + c] = x[idx];
    }
}

// ---- K1 (fused): edge_attr stats partials + histogram + within-node rank ----
__global__ void stats_rel_kernel(const float* __restrict__ ea, const int* __restrict__ ei,
                                 int E, double* __restrict__ acc, int* __restrict__ cnt,
                                 int* __restrict__ rel_t, int* __restrict__ rel_s) {
    __shared__ double sh[4][256];
    int tid = threadIdx.x;
    double s0 = 0, q0 = 0, s1 = 0, q1 = 0;
    for (int i = blockIdx.x * blockDim.x + tid; i < E; i += gridDim.x * blockDim.x) {
        float a = ea[2 * i];
        float b = ea[2 * i + 1];
        s0 += (double)a; q0 += (double)a * (double)a;
        s1 += (double)b; q1 += (double)b * (double)b;
        rel_t[i] = atomicAdd(&cnt[ei[E + i]], 1);  // tgt (+g)
        rel_s[i] = atomicAdd(&cnt[ei[i]], 1);      // src (-g)
    }
    sh[0][tid] = s0; sh[1][tid] = q0; sh[2][tid] = s1; sh[3][tid] = q1;
    __syncthreads();
    for (int off = 128; off > 0; off >>= 1) {
        if (tid < off) {
            sh[0][tid] += sh[0][tid + off];
            sh[1][tid] += sh[1][tid + off];
            sh[2][tid] += sh[2][tid + off];
            sh[3][tid] += sh[3][tid + off];
        }
        __syncthreads();
    }
    if (tid == 0) {
        atomicAdd(&acc[0], sh[0][0]);
        atomicAdd(&acc[1], sh[1][0]);
        atomicAdd(&acc[2], sh[2][0]);
        atomicAdd(&acc[3], sh[3][0]);
    }
}

// ---- K2 (fused): exclusive scan over node counts + stats finalize ----
__global__ __launch_bounds__(1024) void scan_kernel(const int* __restrict__ cnt,
                                                    int* __restrict__ off, int N,
                                                    const double* __restrict__ acc, int E,
                                                    float* __restrict__ stats) {
    if (threadIdx.x == 0) {
        double s0 = acc[0], q0 = acc[1], s1 = acc[2], q1 = acc[3];
        double v0 = (q0 - s0 * s0 / E) / (double)(E - 1);
        double v1 = (q1 - s1 * s1 / E) / (double)(E - 1);
        stats[0] = (float)(s0 / E);
        stats[1] = (float)(1.0 / sqrt(v0));
        stats[2] = (float)(s1 / E);
        stats[3] = (float)(1.0 / sqrt(v1));
    }
    __shared__ int sh[1024];
    int t = threadIdx.x;
    int chunk = (N + 1023) >> 10;
    int lo = t * chunk;
    int hi = lo + chunk; if (hi > N) hi = N;
    int s = 0;
    for (int i = lo; i < hi; i++) s += cnt[i];
    sh[t] = s;
    __syncthreads();
    for (int d = 1; d < 1024; d <<= 1) {
        int v = (t >= d) ? sh[t - d] : 0;
        __syncthreads();
        sh[t] += v;
        __syncthreads();
    }
    int run = (t == 0) ? 0 : sh[t - 1];
    for (int i = lo; i < hi; i++) {
        off[i] = run;
        run += cnt[i];
    }
    if (t == 1023) off[N] = sh[1023];
}

// ---- the 9->16->30->(@W3) MLP: packed fp32 FMA, scalar weight loads ----
__device__ __forceinline__ void mlp_eval(
    const float feat[9],
    const float* __restrict__ W1, const float* __restrict__ b1,
    const float* __restrict__ W2, const float* __restrict__ b2,
    const float* __restrict__ W3,
    float& g0, float& g1, float& g2)
{
    const f32x2* W1p = (const f32x2*)W1;   // [9][8] pairs along j
    const f32x2* b1p = (const f32x2*)b1;
    f32x2 acc1[8];
    #pragma unroll
    for (int j = 0; j < 8; j++) acc1[j] = b1p[j];
    #pragma unroll
    for (int k = 0; k < 9; k++) {
        f32x2 fk2 = {feat[k], feat[k]};
        #pragma unroll
        for (int j = 0; j < 8; j++)
            acc1[j] = __builtin_elementwise_fma(fk2, W1p[k * 8 + j], acc1[j]);
    }
    float h1[16];
    #pragma unroll
    for (int j = 0; j < 8; j++) {
        h1[2 * j]     = sigmoidf_(acc1[j].x);
        h1[2 * j + 1] = sigmoidf_(acc1[j].y);
    }

    const f32x2* W2p = (const f32x2*)W2;   // [16][15] pairs along k
    const f32x2* b2p = (const f32x2*)b2;
    f32x2 acc2[15];
    #pragma unroll
    for (int k = 0; k < 15; k++) acc2[k] = b2p[k];
    #pragma unroll
    for (int j = 0; j < 16; j++) {
        f32x2 hj2 = {h1[j], h1[j]};
        #pragma unroll
        for (int k = 0; k < 15; k++)
            acc2[k] = __builtin_elementwise_fma(hj2, W2p[j * 15 + k], acc2[k]);
    }

    g0 = 0.f; g1 = 0.f; g2 = 0.f;
    #pragma unroll
    for (int k = 0; k < 15; k++) {
        float ha = sigmoidf_(acc2[k].x);
        float hb = sigmoidf_(acc2[k].y);
        int ka = 2 * k, kb = 2 * k + 1;
        g0 = fmaf(ha, W3[ka * 3 + 0], g0); g0 = fmaf(hb, W3[kb * 3 + 0], g0);
        g1 = fmaf(ha, W3[ka * 3 + 1], g1); g1 = fmaf(hb, W3[kb * 3 + 1], g1);
        g2 = fmaf(ha, W3[ka * 3 + 2], g2); g2 = fmaf(hb, W3[kb * 3 + 2], g2);
    }
}

// ---- K3: block = 32 edges x 8 batches; gbuf[E][8] -> wave-linear stores ----
__global__ __launch_bounds__(256) void edge_mlp_kernel(
    const float* __restrict__ xT, const int* __restrict__ ei,
    const float* __restrict__ ea,
    const float* __restrict__ wmean, const float* __restrict__ wstd,
    const float* __restrict__ W1, const float* __restrict__ b1,
    const float* __restrict__ W2, const float* __restrict__ b2,
    const float* __restrict__ W3,
    const float* __restrict__ stats,
    const int* __restrict__ rel_t, const int* __restrict__ rel_s,
    const int* __restrict__ off,
    uint2* __restrict__ gbuf, int* __restrict__ list,
    int N, int E)
{
    int tid = threadIdx.x;
    int b = tid & 7;
    int e = blockIdx.x * 32 + (tid >> 3);
    if (e >= E) return;

    int src = ei[e];
    int tgt = ei[E + e];

    if (b == 0) {
        // slot assignment + list entries (sign in MSB: set => src side, -g)
        list[off[tgt] + rel_t[e]] = e;
        list[off[src] + rel_s[e]] = e | 0x80000000;
    }

    float dist = ea[2 * e];
    float cdir = ea[2 * e + 1];
    float ea0 = (dist - stats[0]) * stats[1];
    float ea1 = (cdir - stats[2]) * stats[3];

    const float* xs = xT + src * 24 + b * 3;   // 8 lanes/edge -> contiguous 96B
    const float* xt = xT + tgt * 24 + b * 3;
    float s0 = xs[0], s1 = xs[1], s2 = xs[2];
    float t0 = xt[0], t1 = xt[1], t2 = xt[2];
    float speed = fmaf(s1, wstd[0], wmean[0]);
    float direc = fmaf(s2, wstd[1], wmean[1]);
    float theta = fabsf(cdir - direc);
    float ew = fmaxf(0.0f, speed * __cosf(theta) * 3.0f * __builtin_amdgcn_rcpf(dist));

    float feat[9] = {s0, s1, s2, t0, t1, t2, ea0, ea1, ew};
    float g0, g1, g2;
    mlp_eval(feat, W1, b1, W2, b2, W3, g0, g1, g2);

    __half2 p01 = __floats2half2_rn(g0, g1);
    __half2 p2x = __floats2half2_rn(g2, 0.0f);
    uint2 wp; wp.x = *reinterpret_cast<unsigned int*>(&p01);
              wp.y = *reinterpret_cast<unsigned int*>(&p2x);
    gbuf[(size_t)e * BB + b] = wp;   // addr == blockIdx*256 + tid : linear
}

// ---- K4: one wave per node; each lane consumes one full 64B edge-line ----
__global__ __launch_bounds__(256) void node_sum_kernel(
    const uint2* __restrict__ gbuf, const int* __restrict__ off,
    const int* __restrict__ list,
    const float* __restrict__ b3, float* __restrict__ out, int N)
{
    int node = blockIdx.x * 4 + (threadIdx.x >> 6);
    int lane = threadIdx.x & 63;
    if (node >= N) return;

    int o0 = off[node], o1 = off[node + 1];
    float a[BB][3];
    #pragma unroll
    for (int b = 0; b < BB; b++) { a[b][0] = 0.f; a[b][1] = 0.f; a[b][2] = 0.f; }

    for (int i = o0 + lane; i < o1; i += 64) {
        int entry = list[i];
        int e = entry & 0x7FFFFFFF;
        float sgn = (entry < 0) ? -1.0f : 1.0f;
        const uint4* gl = reinterpret_cast<const uint4*>(gbuf + (size_t)e * BB);
        uint4 q0 = gl[0], q1 = gl[1], q2 = gl[2], q3 = gl[3];  // 64B: all 8 batches

        #define ACC_(bi, u01, u2x) {                                              \
            float2 f01 = __half22float2(*reinterpret_cast<const __half2*>(&u01)); \
            float2 f2  = __half22float2(*reinterpret_cast<const __half2*>(&u2x)); \
            a[bi][0] = fmaf(sgn, f01.x, a[bi][0]);                                \
            a[bi][1] = fmaf(sgn, f01.y, a[bi][1]);                                \
            a[bi][2] = fmaf(sgn, f2.x,  a[bi][2]); }
        ACC_(0, q0.x, q0.y) ACC_(1, q0.z, q0.w)
        ACC_(2, q1.x, q1.y) ACC_(3, q1.z, q1.w)
        ACC_(4, q2.x, q2.y) ACC_(5, q2.z, q2.w)
        ACC_(6, q3.x, q3.y) ACC_(7, q3.z, q3.w)
        #undef ACC_
    }

    // 64-lane butterfly over all 24 accumulators (static indices only)
    #pragma unroll
    for (int m = 32; m >= 1; m >>= 1) {
        #pragma unroll
        for (int b = 0; b < BB; b++) {
            a[b][0] += __shfl_xor(a[b][0], m);
            a[b][1] += __shfl_xor(a[b][1], m);
            a[b][2] += __shfl_xor(a[b][2], m);
        }
    }

    float bb0 = b3[0], bb1 = b3[1], bb2 = b3[2];
    #pragma unroll
    for (int b = 0; b < BB; b++) {
        if (lane == b) {
            float* o = out + ((size_t)b * N + node) * 3;
            o[0] = sigmoidf_(a[b][0] + bb0);
            o[1] = sigmoidf_(a[b][1] + bb1);
            o[2] = sigmoidf_(a[b][2] + bb2);
        }
    }
}

// ---- Fallback (small ws): atomic-scatter path ----
__global__ __launch_bounds__(256) void edge_atomic_kernel(
    const float* __restrict__ x, const int* __restrict__ ei,
    const float* __restrict__ ea,
    const float* __restrict__ wmean, const float* __restrict__ wstd,
    const float* __restrict__ W1, const float* __restrict__ b1,
    const float* __restrict__ W2, const float* __restrict__ b2,
    const float* __restrict__ W3,
    const float* __restrict__ stats,
    float* __restrict__ out, int N, int E)
{
    int e = blockIdx.x * blockDim.x + threadIdx.x;
    if (e >= E) return;
    int src = ei[e];
    int tgt = ei[E + e];
    float dist = ea[2 * e];
    float cdir = ea[2 * e + 1];
    float ea0 = (dist - stats[0]) * stats[1];
    float ea1 = (cdir - stats[2]) * stats[3];

    for (int b = 0; b < BB; b++) {
        const float* xb = x + (size_t)b * N * 3;
        float s0 = xb[src * 3 + 0], s1 = xb[src * 3 + 1], s2 = xb[src * 3 + 2];
        float t0 = xb[tgt * 3 + 0], t1 = xb[tgt * 3 + 1], t2 = xb[tgt * 3 + 2];
        float speed = fmaf(s1, wstd[0], wmean[0]);
        float direc = fmaf(s2, wstd[1], wmean[1]);
        float theta = fabsf(cdir - direc);
        float ew = fmaxf(0.0f, speed * __cosf(theta) * 3.0f * __builtin_amdgcn_rcpf(dist));
        float feat[9] = {s0, s1, s2, t0, t1, t2, ea0, ea1, ew};
        float g0, g1, g2;
        mlp_eval(feat, W1, b1, W2, b2, W3, g0, g1, g2);
        float* ot = out + ((size_t)b * N + tgt) * 3;
        float* os = out + ((size_t)b * N + src) * 3;
        atomicAdd(&ot[0], g0);  atomicAdd(&ot[1], g1);  atomicAdd(&ot[2], g2);
        atomicAdd(&os[0], -g0); atomicAdd(&os[1], -g1); atomicAdd(&os[2], -g2);
    }
}

__global__ void output_kernel(float* __restrict__ out, const float* __restrict__ b3, int total) {
    int i = blockIdx.x * blockDim.x + threadIdx.x;
    if (i < total) out[i] = sigmoidf_(out[i] + b3[i % 3]);
}

extern "C" void kernel_launch(void* const* d_in, const int* in_sizes, int n_in,
                              void* d_out, int out_size, void* d_ws, size_t ws_size,
                              hipStream_t stream) {
    const float* x     = (const float*)d_in[0];
    const int*   ei    = (const int*)d_in[1];
    const float* ea    = (const float*)d_in[2];
    const float* wmean = (const float*)d_in[3];
    const float* wstd  = (const float*)d_in[4];
    const float* W1    = (const float*)d_in[5];
    const float* b1    = (const float*)d_in[6];
    const float* W2    = (const float*)d_in[7];
    const float* b2    = (const float*)d_in[8];
    const float* W3    = (const float*)d_in[9];
    const float* b3    = (const float*)d_in[10];

    int E = in_sizes[2] / 2;        // edge_attr is (E, 2)
    int N = in_sizes[0] / (BB * 3); // x is (B, N, 3)

    float* out = (float*)d_out;
    char* ws = (char*)d_ws;

    // layout: [cnt N][acc 4 dbl][stats 4 f][off N+1][rel_t E][rel_s E][list 2E][xT N*24 f][gbuf E*8 uint2]
    size_t cntBytes = (((size_t)N * 4) + 63) & ~(size_t)63;
    int*    cnt   = (int*)ws;
    double* acc   = (double*)(ws + cntBytes);        // 32 B
    float*  stats = (float*)(ws + cntBytes + 32);    // 16 B
    int*    off   = (int*)(ws + cntBytes + 64);      // N+1
    int*    rel_t = off + N + 1;                     // E
    int*    rel_s = rel_t + E;                       // E
    int*    list  = rel_s + E;                       // 2E

    size_t xtOff = cntBytes + 64 + sizeof(int) * ((size_t)(N + 1) + 4 * (size_t)E);
    xtOff = (xtOff + 255) & ~(size_t)255;
    float* xT = (float*)(ws + xtOff);

    size_t gbOff = xtOff + (size_t)N * 24 * sizeof(float);
    gbOff = (gbOff + 255) & ~(size_t)255;
    uint2* gbuf = (uint2*)(ws + gbOff);
    size_t needed = gbOff + (size_t)E * BB * sizeof(uint2);

    int eblocks = (E + 255) / 256;

    if (needed <= ws_size) {
        hipMemsetAsync(ws, 0, cntBytes + 32, stream);  // zero cnt + acc
        int xtotal = N * BB * 3;
        transpose_x_kernel<<<(xtotal + 255) / 256, 256, 0, stream>>>(x, xT, N, xtotal);
        stats_rel_kernel<<<512, 256, 0, stream>>>(ea, ei, E, acc, cnt, rel_t, rel_s);
        scan_kernel<<<1, 1024, 0, stream>>>(cnt, off, N, acc, E, stats);
        edge_mlp_kernel<<<(E + 31) / 32, 256, 0, stream>>>(
            xT, ei, ea, wmean, wstd, W1, b1, W2, b2, W3, stats,
            rel_t, rel_s, off, gbuf, list, N, E);
        node_sum_kernel<<<(N + 3) / 4, 256, 0, stream>>>(
            gbuf, off, list, b3, out, N);
    } else {
        hipMemsetAsync(ws, 0, cntBytes + 32, stream);
        hipMemsetAsync(d_out, 0, (size_t)out_size * sizeof(float), stream);
        stats_rel_kernel<<<512, 256, 0, stream>>>(ea, ei, E, acc, cnt, rel_t, rel_s);
        scan_kernel<<<1, 1024, 0, stream>>>(cnt, off, N, acc, E, stats);
        edge_atomic_kernel<<<eblocks, 256, 0, stream>>>(
            x, ei, ea, wmean, wstd, W1, b1, W2, b2, W3, stats, out, N, E);
        output_kernel<<<(out_size + 255) / 256, 256, 0, stream>>>(out, b3, out_size);
    }
}